// Round 2
// baseline (86.210 us; speedup 1.0000x reference)
//
#include <hip/hip_runtime.h>
#include <math.h>

#define HIDDEN 1024
#define VOCAB  50257
#define MAXLEN 64

__device__ __forceinline__ float wave_reduce_sum(float v) {
    #pragma unroll
    for (int off = 32; off > 0; off >>= 1)
        v += __shfl_down(v, off, 64);
    return v;
}

// K1: fused scores + softmax + context + combine.
// 256 blocks x 256 threads; block b computes combine rows 4b..4b+3.
// Each block redundantly recomputes scores/softmax/context from L2-resident
// attn_W (512KB) and enc (256KB) — cheaper than 3 extra kernel launches.
__global__ __launch_bounds__(256) void k_pre(
    const int* __restrict__ token,
    const float* __restrict__ emb,
    const float* __restrict__ hidden,
    const float* __restrict__ enc,
    const float* __restrict__ attn_W,
    const float* __restrict__ attn_b,
    const float* __restrict__ comb_W,
    const float* __restrict__ comb_b,
    float* __restrict__ ws_x,
    float* __restrict__ out_attn)
{
    __shared__ float cvec[2 * HIDDEN];   // concat(emb_row, h0), later concat(emb_row, ctx)
    __shared__ float sc[MAXLEN];
    __shared__ float wsm[MAXLEN];

    const int t = threadIdx.x;
    const int wid = t >> 6, lane = t & 63;
    const float* erow = emb + (size_t)token[0] * HIDDEN;

    // stage concat(emb_row, h0): 512 float4s, 2 per thread
    {
        float4* cv4 = (float4*)cvec;
        cv4[t]       = ((const float4*)erow)[t];
        cv4[t + 256] = ((const float4*)hidden)[t];
    }
    __syncthreads();

    // scores: wave wid computes rows m = wid, wid+4, ... (16 rows/wave)
    for (int m = wid; m < MAXLEN; m += 4) {
        const float4* Wr  = (const float4*)(attn_W + (size_t)m * 2 * HIDDEN);
        const float4* cv4 = (const float4*)cvec;
        float acc = 0.f;
        #pragma unroll
        for (int it = 0; it < 8; ++it) {
            int i = lane + it * 64;
            float4 a = Wr[i]; float4 b = cv4[i];
            acc += a.x * b.x + a.y * b.y + a.z * b.z + a.w * b.w;
        }
        acc = wave_reduce_sum(acc);
        if (lane == 0) sc[m] = acc + attn_b[m];
    }
    __syncthreads();

    // softmax over 64 scores in wave 0
    if (wid == 0) {
        float s = sc[lane];
        float mx = s;
        #pragma unroll
        for (int off = 32; off > 0; off >>= 1) mx = fmaxf(mx, __shfl_xor(mx, off, 64));
        float e = expf(s - mx);
        float sum = e;
        #pragma unroll
        for (int off = 32; off > 0; off >>= 1) sum += __shfl_xor(sum, off, 64);
        float wv = e / sum;
        wsm[lane] = wv;
        if (blockIdx.x == 0) out_attn[lane] = wv;
    }
    __syncthreads();

    // context -> cvec[1024:2048]; each thread owns 4 columns
    {
        float a0 = 0.f, a1 = 0.f, a2 = 0.f, a3 = 0.f;
        #pragma unroll 4
        for (int m = 0; m < MAXLEN; ++m) {
            float wv = wsm[m];
            const float* er = enc + (size_t)m * HIDDEN;
            a0 += wv * er[t];
            a1 += wv * er[t + 256];
            a2 += wv * er[t + 512];
            a3 += wv * er[t + 768];
        }
        cvec[HIDDEN + t]       = a0;
        cvec[HIDDEN + t + 256] = a1;
        cvec[HIDDEN + t + 512] = a2;
        cvec[HIDDEN + t + 768] = a3;
    }
    __syncthreads();

    // combine: wave wid -> row j = 4*blockIdx + wid
    {
        const int j = blockIdx.x * 4 + wid;
        const float4* Wr  = (const float4*)(comb_W + (size_t)j * 2 * HIDDEN);
        const float4* cv4 = (const float4*)cvec;
        float acc = 0.f;
        #pragma unroll
        for (int it = 0; it < 8; ++it) {
            int i = lane + it * 64;
            float4 a = Wr[i]; float4 b = cv4[i];
            acc += a.x * b.x + a.y * b.y + a.z * b.z + a.w * b.w;
        }
        acc = wave_reduce_sum(acc);
        if (lane == 0) ws_x[j] = fmaxf(acc + comb_b[j], 0.f);
    }
}

// K2: GRU step. 256 blocks x 256 threads, wave per output element j.
__global__ __launch_bounds__(256) void k_gru(
    const float* __restrict__ ws_x,
    const float* __restrict__ hidden,
    const float* __restrict__ W_ih,
    const float* __restrict__ W_hh,
    const float* __restrict__ b_ih,
    const float* __restrict__ b_hh,
    float* __restrict__ ws_h,
    float* __restrict__ out_h)
{
    const int wid = threadIdx.x >> 6, lane = threadIdx.x & 63;
    const int j = blockIdx.x * 4 + wid;
    float d[6];
    const float* rows[6] = {
        W_ih + (size_t)j * HIDDEN,
        W_ih + (size_t)(j + HIDDEN) * HIDDEN,
        W_ih + (size_t)(j + 2 * HIDDEN) * HIDDEN,
        W_hh + (size_t)j * HIDDEN,
        W_hh + (size_t)(j + HIDDEN) * HIDDEN,
        W_hh + (size_t)(j + 2 * HIDDEN) * HIDDEN };
    const float* vecs[2] = { ws_x, hidden };
    #pragma unroll
    for (int q = 0; q < 6; ++q) {
        const float4* W4 = (const float4*)rows[q];
        const float4* v4 = (const float4*)vecs[q / 3];
        float acc = 0.f;
        #pragma unroll
        for (int it = 0; it < 4; ++it) {
            int i = lane + it * 64;
            float4 a = W4[i];
            float4 b = v4[i];
            acc += a.x * b.x + a.y * b.y + a.z * b.z + a.w * b.w;
        }
        d[q] = wave_reduce_sum(acc);
    }
    if (lane == 0) {
        float i_r = d[0] + b_ih[j];
        float i_z = d[1] + b_ih[j + HIDDEN];
        float i_n = d[2] + b_ih[j + 2 * HIDDEN];
        float h_r = d[3] + b_hh[j];
        float h_z = d[4] + b_hh[j + HIDDEN];
        float h_n = d[5] + b_hh[j + 2 * HIDDEN];
        float r = 1.f / (1.f + expf(-(i_r + h_r)));
        float z = 1.f / (1.f + expf(-(i_z + h_z)));
        float n = tanhf(i_n + r * h_n);
        float h0v = hidden[j];
        float hn = (1.f - z) * n + z * h0v;
        ws_h[j] = hn;
        out_h[j] = hn;
    }
}

// K3: logits. 8 rows/block (2 per wave, independent accumulators for ILP).
__global__ __launch_bounds__(256) void k_logits(
    const float* __restrict__ ws_h,
    const float* __restrict__ out_W,
    const float* __restrict__ out_b,
    float* __restrict__ out_logits)
{
    __shared__ float4 hn[HIDDEN / 4];
    const int t = threadIdx.x;
    hn[t] = ((const float4*)ws_h)[t];
    __syncthreads();
    const int wid = t >> 6, lane = t & 63;
    const int v0 = blockIdx.x * 8 + wid * 2;
    const int v1 = v0 + 1;
    if (v0 >= VOCAB) return;
    const float4* W0 = (const float4*)(out_W + (size_t)v0 * HIDDEN);
    const float4* W1 = (const float4*)(out_W + (size_t)v1 * HIDDEN);
    const bool has1 = (v1 < VOCAB);
    float acc0 = 0.f, acc1 = 0.f;
    #pragma unroll
    for (int i = 0; i < 4; ++i) {
        const int idx = lane + i * 64;
        float4 b = hn[idx];
        float4 a0 = W0[idx];
        acc0 += a0.x * b.x + a0.y * b.y + a0.z * b.z + a0.w * b.w;
        if (has1) {
            float4 a1 = W1[idx];
            acc1 += a1.x * b.x + a1.y * b.y + a1.z * b.z + a1.w * b.w;
        }
    }
    acc0 = wave_reduce_sum(acc0);
    acc1 = wave_reduce_sum(acc1);
    if (lane == 0) {
        out_logits[v0] = acc0 + out_b[v0];
        if (has1) out_logits[v1] = acc1 + out_b[v1];
    }
}

extern "C" void kernel_launch(void* const* d_in, const int* in_sizes, int n_in,
                              void* d_out, int out_size, void* d_ws, size_t ws_size,
                              hipStream_t stream) {
    const int*   token  = (const int*)d_in[0];
    const float* hidden = (const float*)d_in[1];
    const float* enc    = (const float*)d_in[2];
    const float* emb    = (const float*)d_in[3];
    const float* attn_W = (const float*)d_in[4];
    const float* attn_b = (const float*)d_in[5];
    const float* comb_W = (const float*)d_in[6];
    const float* comb_b = (const float*)d_in[7];
    const float* W_ih   = (const float*)d_in[8];
    const float* W_hh   = (const float*)d_in[9];
    const float* b_ih   = (const float*)d_in[10];
    const float* b_hh   = (const float*)d_in[11];
    const float* out_W  = (const float*)d_in[12];
    const float* out_b  = (const float*)d_in[13];

    float* out = (float*)d_out;
    float* out_logits = out;                       // [50257]
    float* out_h      = out + VOCAB;               // [1024]
    float* out_attn   = out + VOCAB + HIDDEN;      // [64]

    float* ws = (float*)d_ws;
    float* ws_x = ws;          // 1024
    float* ws_h = ws + 1024;   // 1024

    k_pre<<<HIDDEN / 4, 256, 0, stream>>>(token, emb, hidden, enc, attn_W, attn_b,
                                          comb_W, comb_b, ws_x, out_attn);
    k_gru<<<HIDDEN / 4, 256, 0, stream>>>(ws_x, hidden, W_ih, W_hh, b_ih, b_hh, ws_h, out_h);
    k_logits<<<(VOCAB + 7) / 8, 256, 0, stream>>>(ws_h, out_W, out_b, out_logits);
}

// Round 3
// 53.614 us; speedup vs baseline: 1.6080x; 1.6080x over previous
//
#include <hip/hip_runtime.h>
#include <math.h>

#define HIDDEN 1024
#define VOCAB  50257
#define MAXLEN 64

__device__ __forceinline__ float wave_reduce_sum(float v) {
    #pragma unroll
    for (int off = 32; off > 0; off >>= 1)
        v += __shfl_down(v, off, 64);
    return v;
}

// 64 blocks x 256 threads: scores[m] = dot(concat(emb_row, h0), attn_W[m]) + attn_b[m]
__global__ void k_scores(const int* __restrict__ token,
                         const float* __restrict__ emb,
                         const float* __restrict__ hidden,
                         const float* __restrict__ attn_W,
                         const float* __restrict__ attn_b,
                         float* __restrict__ ws_scores) {
    const int m = blockIdx.x;
    const int t = threadIdx.x;
    const float* erow = emb + (size_t)token[0] * HIDDEN;
    const float4* Wrow = (const float4*)(attn_W + (size_t)m * 2 * HIDDEN);
    float acc = 0.f;
    #pragma unroll
    for (int it = 0; it < 2; ++it) {
        int i = t + it * 256;            // 0..511 float4s
        float4 w4 = Wrow[i];
        int k = i * 4;
        const float* src = (k < HIDDEN) ? (erow + k) : (hidden + k - HIDDEN);
        float4 c4 = *(const float4*)src;
        acc += w4.x * c4.x + w4.y * c4.y + w4.z * c4.z + w4.w * c4.w;
    }
    __shared__ float part[4];
    acc = wave_reduce_sum(acc);
    const int wid = t >> 6, lane = t & 63;
    if (lane == 0) part[wid] = acc;
    __syncthreads();
    if (t == 0)
        ws_scores[m] = part[0] + part[1] + part[2] + part[3] + attn_b[m];
}

// 4 blocks x 256 threads: per-block redundant softmax (1 wave, 64 elems) + context.
// ctx[h] = sum_m softmax(scores)[m] * enc[m][h]
__global__ void k_smctx(const float* __restrict__ ws_scores,
                        const float* __restrict__ enc,
                        float* __restrict__ ws_ctx,
                        float* __restrict__ out_attn) {
    __shared__ float wsm[MAXLEN];
    const int t = threadIdx.x;
    const int wid = t >> 6, lane = t & 63;
    if (wid == 0) {
        float s = ws_scores[lane];
        float mx = s;
        #pragma unroll
        for (int off = 32; off > 0; off >>= 1) mx = fmaxf(mx, __shfl_xor(mx, off, 64));
        float e = expf(s - mx);
        float sum = e;
        #pragma unroll
        for (int off = 32; off > 0; off >>= 1) sum += __shfl_xor(sum, off, 64);
        float wv = e / sum;
        wsm[lane] = wv;
        if (blockIdx.x == 0) out_attn[lane] = wv;
    }
    __syncthreads();
    const int h = blockIdx.x * 256 + t;
    float acc = 0.f;
    #pragma unroll 8
    for (int m = 0; m < MAXLEN; ++m)
        acc += wsm[m] * enc[(size_t)m * HIDDEN + h];
    ws_ctx[h] = acc;
}

// 256 blocks x 256 threads (wave per row): x[j] = relu(dot(concat(emb_row, ctx), comb_W[j]) + comb_b[j])
__global__ void k_combine(const int* __restrict__ token,
                          const float* __restrict__ emb,
                          const float* __restrict__ ws_ctx,
                          const float* __restrict__ comb_W,
                          const float* __restrict__ comb_b,
                          float* __restrict__ ws_x) {
    const int wid = threadIdx.x >> 6, lane = threadIdx.x & 63;
    const int j = blockIdx.x * 4 + wid;
    const float* erow = emb + (size_t)token[0] * HIDDEN;
    const float4* Wrow = (const float4*)(comb_W + (size_t)j * 2 * HIDDEN);
    float acc = 0.f;
    #pragma unroll
    for (int it = 0; it < 8; ++it) {
        int i = lane + it * 64;          // 0..511 float4s
        float4 w4 = Wrow[i];
        int k = i * 4;
        const float* src = (k < HIDDEN) ? (erow + k) : (ws_ctx + k - HIDDEN);
        float4 c4 = *(const float4*)src;
        acc += w4.x * c4.x + w4.y * c4.y + w4.z * c4.z + w4.w * c4.w;
    }
    acc = wave_reduce_sum(acc);
    if (lane == 0) ws_x[j] = fmaxf(acc + comb_b[j], 0.f);
}

// 1024 blocks x 384 threads: block j, wave q in 0..5 computes gate-dot q for
// output element j; thread 0 combines with GRU gate math.
__global__ __launch_bounds__(384) void k_gru(
    const float* __restrict__ ws_x,
    const float* __restrict__ hidden,
    const float* __restrict__ W_ih,
    const float* __restrict__ W_hh,
    const float* __restrict__ b_ih,
    const float* __restrict__ b_hh,
    float* __restrict__ ws_h,
    float* __restrict__ out_h)
{
    __shared__ float dval[6];
    const int j = blockIdx.x;
    const int q = threadIdx.x >> 6, lane = threadIdx.x & 63;
    const float* row = (q < 3)
        ? (W_ih + (size_t)(j + q * HIDDEN) * HIDDEN)
        : (W_hh + (size_t)(j + (q - 3) * HIDDEN) * HIDDEN);
    const float* vec = (q < 3) ? ws_x : hidden;
    const float4* W4 = (const float4*)row;
    const float4* v4 = (const float4*)vec;
    float acc = 0.f;
    #pragma unroll
    for (int it = 0; it < 4; ++it) {
        int i = lane + it * 64;          // 0..255 float4s
        float4 a = W4[i];
        float4 b = v4[i];
        acc += a.x * b.x + a.y * b.y + a.z * b.z + a.w * b.w;
    }
    acc = wave_reduce_sum(acc);
    if (lane == 0) dval[q] = acc;
    __syncthreads();
    if (threadIdx.x == 0) {
        float i_r = dval[0] + b_ih[j];
        float i_z = dval[1] + b_ih[j + HIDDEN];
        float i_n = dval[2] + b_ih[j + 2 * HIDDEN];
        float h_r = dval[3] + b_hh[j];
        float h_z = dval[4] + b_hh[j + HIDDEN];
        float h_n = dval[5] + b_hh[j + 2 * HIDDEN];
        float r = 1.f / (1.f + expf(-(i_r + h_r)));
        float z = 1.f / (1.f + expf(-(i_z + h_z)));
        float n = tanhf(i_n + r * h_n);
        float h0v = hidden[j];
        float hn = (1.f - z) * n + z * h0v;
        ws_h[j] = hn;
        out_h[j] = hn;
    }
}

// ceil(VOCAB/4) blocks x 256 threads (wave per vocab row): logits[v] = dot(h_new, out_W[v]) + out_b[v]
__global__ void k_logits(const float* __restrict__ ws_h,
                         const float* __restrict__ out_W,
                         const float* __restrict__ out_b,
                         float* __restrict__ out_logits) {
    __shared__ float4 hn[HIDDEN / 4];
    const int t = threadIdx.x;
    hn[t] = ((const float4*)ws_h)[t];
    __syncthreads();
    const int wid = t >> 6, lane = t & 63;
    const int v = blockIdx.x * 4 + wid;
    if (v >= VOCAB) return;
    const float4* Wrow = (const float4*)(out_W + (size_t)v * HIDDEN);
    float acc = 0.f;
    #pragma unroll
    for (int i = 0; i < 4; ++i) {
        float4 a = Wrow[lane + i * 64];
        float4 b = hn[lane + i * 64];
        acc += a.x * b.x + a.y * b.y + a.z * b.z + a.w * b.w;
    }
    acc = wave_reduce_sum(acc);
    if (lane == 0) out_logits[v] = acc + out_b[v];
}

extern "C" void kernel_launch(void* const* d_in, const int* in_sizes, int n_in,
                              void* d_out, int out_size, void* d_ws, size_t ws_size,
                              hipStream_t stream) {
    const int*   token  = (const int*)d_in[0];
    const float* hidden = (const float*)d_in[1];
    const float* enc    = (const float*)d_in[2];
    const float* emb    = (const float*)d_in[3];
    const float* attn_W = (const float*)d_in[4];
    const float* attn_b = (const float*)d_in[5];
    const float* comb_W = (const float*)d_in[6];
    const float* comb_b = (const float*)d_in[7];
    const float* W_ih   = (const float*)d_in[8];
    const float* W_hh   = (const float*)d_in[9];
    const float* b_ih   = (const float*)d_in[10];
    const float* b_hh   = (const float*)d_in[11];
    const float* out_W  = (const float*)d_in[12];
    const float* out_b  = (const float*)d_in[13];

    float* out = (float*)d_out;
    float* out_logits = out;                       // [50257]
    float* out_h      = out + VOCAB;               // [1024]
    float* out_attn   = out + VOCAB + HIDDEN;      // [64]

    float* ws = (float*)d_ws;
    float* ws_scores = ws;            // 64
    float* ws_ctx    = ws + 64;       // 1024
    float* ws_x      = ws + 1088;     // 1024
    float* ws_h      = ws + 2112;     // 1024

    k_scores<<<MAXLEN, 256, 0, stream>>>(token, emb, hidden, attn_W, attn_b, ws_scores);
    k_smctx<<<HIDDEN / 256, 256, 0, stream>>>(ws_scores, enc, ws_ctx, out_attn);
    k_combine<<<HIDDEN / 4, 256, 0, stream>>>(token, emb, ws_ctx, comb_W, comb_b, ws_x);
    k_gru<<<HIDDEN, 384, 0, stream>>>(ws_x, hidden, W_ih, W_hh, b_ih, b_hh, ws_h, out_h);
    k_logits<<<(VOCAB + 3) / 4, 256, 0, stream>>>(ws_h, out_W, out_b, out_logits);
}